// Round 1
// baseline (73.169 us; speedup 1.0000x reference)
//
#include <hip/hip_runtime.h>

constexpr int N = 512;   // number of samples
constexpr int D = 256;   // feature dim
#define MARGIN 1.0f

__device__ __forceinline__ float dot4(const float4 a, const float4 b) {
  return a.x * b.x + a.y * b.y + a.z * b.z + a.w * b.w;
}

// K1: pairwise distances via the reference's own identity
//   d^2(i,j) = |xi|^2 + |xj|^2 - 2 xi.xj
// Grid = 64 anchor-tiles x 4 col-tiles = 256 blocks (1/CU), 512 threads.
// Each block keeps 8 anchor rows in registers (lane `sub` owns a 16-elem
// k-slice: 4 float4 per anchor) and streams 128 col rows from L2:
// 8 KB + 128 KB = 136 KB per block vs 512 KB in the previous layout.
// 9 fma/element (8 dots + on-the-fly col norm), 16-lane shfl_xor butterfly,
// d written to a padded LDS tile and flushed coalesced to dist[512][512].
__global__ __launch_bounds__(512, 2) void dist_kernel(
    const float* __restrict__ x, float* __restrict__ dist,
    int* __restrict__ ticket) {
  const int b = blockIdx.x;
  const int at = b >> 2;                    // 0..63  anchor tile (8 rows)
  const int ct = b & 3;                     // 0..3   col tile (128 rows)
  const int tid = threadIdx.x;              // 512 threads = 8 waves
  const int wave = tid >> 6, lane = tid & 63;
  const int sub = lane & 15, rg = lane >> 4;

  if (b == 0 && tid == 0) *ticket = 0;      // re-arm K2's last-block ticket

  // 8 anchor fragments in registers (fully unrolled -> no scratch)
  float4 fa[8][4];
  #pragma unroll
  for (int a = 0; a < 8; ++a) {
    const float4* xa = (const float4*)(x + (size_t)(8 * at + a) * D);
    #pragma unroll
    for (int q = 0; q < 4; ++q) fa[a][q] = xa[q * 16 + sub];
  }
  // anchor norms |xa|^2 (every lane ends with the full sum)
  float sqa[8];
  #pragma unroll
  for (int a = 0; a < 8; ++a) {
    float s = dot4(fa[a][0], fa[a][0]) + dot4(fa[a][1], fa[a][1]) +
              dot4(fa[a][2], fa[a][2]) + dot4(fa[a][3], fa[a][3]);
    #pragma unroll
    for (int m = 1; m < 16; m <<= 1) s += __shfl_xor(s, m);
    sqa[a] = s;
  }

  // +4 pad: 132 % 32 = 4 -> the 8 column-writers hit 8 distinct banks
  __shared__ float dtile[8][132];

  // wave w covers local cols [16w, 16w+16): 4 iters x 4 rows (one per group)
  #pragma unroll 2
  for (int it = 0; it < 4; ++it) {
    const int l = wave * 16 + it * 4 + rg;  // 0..127
    const float4* xr = (const float4*)(x + (size_t)(ct * 128 + l) * D);
    float4 b0 = xr[sub], b1 = xr[16 + sub], b2 = xr[32 + sub],
           b3 = xr[48 + sub];
    float nr = dot4(b0, b0) + dot4(b1, b1) + dot4(b2, b2) + dot4(b3, b3);
    float dp[8];
    #pragma unroll
    for (int a = 0; a < 8; ++a)
      dp[a] = dot4(fa[a][0], b0) + dot4(fa[a][1], b1) + dot4(fa[a][2], b2) +
              dot4(fa[a][3], b3);
    // 16-lane butterflies: every lane gets all 8 dots + the col norm
    #pragma unroll
    for (int m = 1; m < 16; m <<= 1) {
      nr += __shfl_xor(nr, m);
      #pragma unroll
      for (int a = 0; a < 8; ++a) dp[a] += __shfl_xor(dp[a], m);
    }
    if (sub < 8) {
      // lane sub takes anchor sub (cndmask chain, compile-time indices only)
      float ds = dp[0], qs = sqa[0];
      #pragma unroll
      for (int a = 1; a < 8; ++a)
        if (sub == a) { ds = dp[a]; qs = sqa[a]; }
      const float dd = qs + nr - 2.0f * ds;
      dtile[sub][l] = sqrtf(fmaxf(dd, 1e-16f));
    }
  }
  __syncthreads();
  // coalesced flush of the 8x128 tile
  for (int j = tid; j < 8 * 128; j += 512) {
    const int a = j >> 7, l = j & 127;
    dist[(size_t)(8 * at + a) * N + ct * 128 + l] = dtile[a][l];
  }
}

// K2: triplet phase. Block b owns anchors i0=2b, i1=2b+1; thread e=tid owns
// element e (dist-row loads are coalesced, m-values stay in registers).
// Positives compacted into LDS; then sum/count relu(c_j - d_ik + 0).
// Finalize is folded in via a ticketed last-block reduction (2 launches total).
__global__ __launch_bounds__(512, 2) void triplet_kernel(
    const float* __restrict__ dist, const int* __restrict__ tgt,
    float* __restrict__ psum, float* __restrict__ pcnt,
    int* __restrict__ ticket, float* __restrict__ out) {
  __shared__ float cl0[N], cl1[N];
  __shared__ int nv0, nv1;
  __shared__ float wred[16];
  __shared__ int lastf;

  const int b = blockIdx.x;
  const int i0 = 2 * b, i1 = 2 * b + 1;
  const int tid = threadIdx.x;              // 512 = one thread per element
  const int wave = tid >> 6, lane = tid & 63;
  const int e = tid;

  if (tid == 0) { nv0 = 0; nv1 = 0; }
  const int t0 = tgt[i0], t1 = tgt[i1];
  const int tj = tgt[e];
  const float d0 = dist[(size_t)i0 * N + e];
  const float d1 = dist[(size_t)i1 * N + e];
  __syncthreads();                          // nv zeroed

  const float m0 = (tj != t0) ? d0 : __builtin_inff();
  const float m1 = (tj != t1) ? d1 : __builtin_inff();
  if (tj == t0 && e != i0) { int s = atomicAdd(&nv0, 1); cl0[s] = d0 + MARGIN; }
  if (tj == t1 && e != i1) { int s = atomicAdd(&nv1, 1); cl1[s] = d1 + MARGIN; }
  __syncthreads();

  float sum = 0.f, cnt = 0.f;
  const int n0 = nv0, n1 = nv1;
  for (int v = 0; v < n0; ++v) {
    const float a = cl0[v] - m0;            // LDS broadcast
    sum += fmaxf(a, 0.f);
    cnt += (a > 1e-16f ? 1.f : 0.f);
  }
  for (int v = 0; v < n1; ++v) {
    const float a = cl1[v] - m1;
    sum += fmaxf(a, 0.f);
    cnt += (a > 1e-16f ? 1.f : 0.f);
  }

  #pragma unroll
  for (int off = 32; off > 0; off >>= 1) {
    sum += __shfl_down(sum, off);
    cnt += __shfl_down(cnt, off);
  }
  if (lane == 0) { wred[wave] = sum; wred[8 + wave] = cnt; }
  __syncthreads();
  if (tid == 0) {
    float s = 0.f, c = 0.f;
    #pragma unroll
    for (int w = 0; w < 8; ++w) { s += wred[w]; c += wred[8 + w]; }
    psum[b] = s;
    pcnt[b] = c;
    __threadfence();                        // publish partials (release)
    const int old = atomicAdd(ticket, 1);   // device-scope
    lastf = (old == 255) ? 1 : 0;
  }
  __syncthreads();                          // lastf uniform across block

  if (lastf) {
    __threadfence();                        // acquire side
    float s = (tid < 256) ? psum[tid] : 0.f;
    float c = (tid < 256) ? pcnt[tid] : 0.f;
    #pragma unroll
    for (int off = 32; off > 0; off >>= 1) {
      s += __shfl_down(s, off);
      c += __shfl_down(c, off);
    }
    if (lane == 0) { wred[wave] = s; wred[8 + wave] = c; }
    __syncthreads();
    if (tid == 0) {
      float ts = 0.f, tc = 0.f;
      #pragma unroll
      for (int w = 0; w < 8; ++w) { ts += wred[w]; tc += wred[8 + w]; }
      out[0] = ts / (tc + 1e-16f);
    }
  }
}

extern "C" void kernel_launch(void* const* d_in, const int* in_sizes, int n_in,
                              void* d_out, int out_size, void* d_ws, size_t ws_size,
                              hipStream_t stream) {
  const float* x = (const float*)d_in[0];   // [512, 256] fp32
  const int* tgt = (const int*)d_in[1];     // [512] int32
  float* out = (float*)d_out;               // scalar fp32

  float* wsf = (float*)d_ws;
  float* psum = wsf;                        // [256]
  float* pcnt = wsf + 256;                  // [256]
  int* ticket = (int*)(wsf + 512);          // [1]
  float* dist = wsf + 1024;                 // [512][512] fp32 = 1 MB

  dist_kernel<<<256, 512, 0, stream>>>(x, dist, ticket);
  triplet_kernel<<<256, 512, 0, stream>>>(dist, tgt, psum, pcnt, ticket, out);
}